// Round 9
// baseline (500.720 us; speedup 1.0000x reference)
//
#include <hip/hip_runtime.h>
#include <math.h>

// Problem constants
#define NN 100000
#define DD 128
#define EE 600000
#define RR 5
#define MCNT (RR * NN)          // 500000 sort buckets (key = dst*5 + rel)
#define NB1 489                 // ceil(MCNT / 1024)

#define WSTR 136                // padded slot stride (f16) for transposed W
#define SLAB 32                 // rows per chunk; 100000 = 3125*32
#define NSLAB (NN / SLAB)
#define BGSTR 264               // film BG row stride (f16): 256 + 8 pad
#define SKSTR 392               // skip buffer row stride (f16): 384 + 8 pad

// prep kernel partitions
#define CONV_BLKS 6250
#define ZERO_BLKS 245           // 245*2048 >= 500000
#define TW_BLKS  1216           // 1216*2 = 2432 weight slots

typedef _Float16 v8h __attribute__((ext_vector_type(8)));
typedef _Float16 h4  __attribute__((ext_vector_type(4)));
typedef float    v4f __attribute__((ext_vector_type(4)));

__device__ __forceinline__ float gelu_exact(float v) {
    return 0.5f * v * (1.0f + erff(v * 0.7071067811865476f));
}

// ---------------------------------------------------------------------------
// prep: fused convert_x (f32->f16) + cnt zero + weight transpose.
// wt layout (slot-major, stride WSTR, wt[slot*WSTR + k]):
//   slots    0..383  : skip set FLAT: s = a*128 + col;
//                      a=0 lin_skip col, a=1 beta_s col, a=2 gamma_s col
//   slots  384..1023 : lins_w  flat: slot = 384 + r*128 + col
//   slots 1024..2303 : films_w flat: slot = 1024 + r*256 + f (f=col of (D,2D))
//   slots 2304..2431 : linear1_w col
// ---------------------------------------------------------------------------
__global__ __launch_bounds__(256)
void prep(const float* __restrict__ x, _Float16* __restrict__ xh,
          int* __restrict__ cnt,
          const float* __restrict__ lin_skip_w,
          const float* __restrict__ film_skip_w,
          const float* __restrict__ lins_w,
          const float* __restrict__ films_w,
          const float* __restrict__ linear1_w,
          _Float16* __restrict__ wt)
{
    const int b = blockIdx.x;
    if (b < CONV_BLKS) {
        size_t u = (size_t)b * 256 + threadIdx.x;
        const float4 a = *(const float4*)(x + u * 8);
        const float4 c = *(const float4*)(x + u * 8 + 4);
        v8h o;
        o[0] = (_Float16)a.x; o[1] = (_Float16)a.y; o[2] = (_Float16)a.z; o[3] = (_Float16)a.w;
        o[4] = (_Float16)c.x; o[5] = (_Float16)c.y; o[6] = (_Float16)c.z; o[7] = (_Float16)c.w;
        *(v8h*)(xh + u * 8) = o;
    } else if (b < CONV_BLKS + ZERO_BLKS) {
        int i = (b - CONV_BLKS) * 2048 + threadIdx.x * 8;
        #pragma unroll
        for (int j = 0; j < 8; ++j)
            if (i + j < MCNT) cnt[i + j] = 0;
    } else {
        const int bb = (b - CONV_BLKS - ZERO_BLKS) * 2 + (threadIdx.x >> 7);
        const int k  = threadIdx.x & 127;
        float v;
        if (bb < 384) {
            const int a   = bb >> 7;          // 0=lin, 1=beta_s, 2=gamma_s
            const int col = bb & 127;
            v = (a == 0) ? lin_skip_w[k * DD + col]
                         : film_skip_w[k * 2 * DD + (a - 1) * DD + col];
        } else if (bb < 1024) {
            const int r = (bb - 384) >> 7;
            const int c = (bb - 384) & 127;
            v = lins_w[((size_t)r * DD + k) * DD + c];
        } else if (bb < 2304) {
            const int r = (bb - 1024) >> 8;
            const int f = (bb - 1024) & 255;
            v = films_w[((size_t)r * DD + k) * 2 * DD + f];
        } else {
            v = linear1_w[k * DD + (bb - 2304)];
        }
        wt[(size_t)bb * WSTR + k] = (_Float16)v;
    }
}

// ---------------------------------------------------------------------------
// Counting sort of edges by key = dst*RR + rel  (dst-major)
// ---------------------------------------------------------------------------
__global__ __launch_bounds__(256)
void count_kernel(const int* __restrict__ ei, const int* __restrict__ et,
                  int* __restrict__ cnt)
{
    int e = blockIdx.x * 256 + threadIdx.x;
    if (e < EE) atomicAdd(&cnt[(size_t)ei[EE + e] * RR + et[e]], 1);
}

__global__ __launch_bounds__(256)
void scan1(const int* __restrict__ cnt, int* __restrict__ partial,
           int* __restrict__ bsum)
{
    __shared__ int s[256];
    const int t = threadIdx.x;
    const int base = blockIdx.x * 1024 + t * 4;
    int v[4], sum = 0;
    #pragma unroll
    for (int j = 0; j < 4; ++j) {
        v[j] = (base + j < MCNT) ? cnt[base + j] : 0;
        sum += v[j];
    }
    s[t] = sum;
    __syncthreads();
    for (int off = 1; off < 256; off <<= 1) {
        int x = (t >= off) ? s[t - off] : 0;
        __syncthreads();
        s[t] += x;
        __syncthreads();
    }
    int run = s[t] - sum;
    if (t == 255) bsum[blockIdx.x] = s[255];
    #pragma unroll
    for (int j = 0; j < 4; ++j) {
        if (base + j < MCNT) partial[base + j] = run;
        run += v[j];
    }
}

__global__ __launch_bounds__(512)
void scan2(const int* __restrict__ bsum, int* __restrict__ bsum2)
{
    __shared__ int s[512];
    const int t = threadIdx.x;
    const int v = (t < NB1) ? bsum[t] : 0;
    s[t] = v;
    __syncthreads();
    for (int off = 1; off < 512; off <<= 1) {
        int x = (t >= off) ? s[t - off] : 0;
        __syncthreads();
        s[t] += x;
        __syncthreads();
    }
    if (t < NB1) bsum2[t] = s[t] - v;
}

__global__ __launch_bounds__(256)
void scan3(const int* __restrict__ partial, const int* __restrict__ bsum2,
           int* __restrict__ rowptr, int* __restrict__ head,
           int* __restrict__ srcs)
{
    const int t = threadIdx.x;
    const int base = blockIdx.x * 1024 + t * 4;
    const int add = bsum2[blockIdx.x];
    #pragma unroll
    for (int j = 0; j < 4; ++j) {
        if (base + j < MCNT) {
            int v = partial[base + j] + add;
            rowptr[base + j] = v;
            head[base + j]   = v;
        }
    }
    if (blockIdx.x == 0 && t == 0) rowptr[MCNT] = EE;
    if (blockIdx.x == 0 && t < 8) srcs[EE + t] = 0;   // pad (defensive)
}

__global__ __launch_bounds__(256)
void scatter_kernel(const int* __restrict__ ei, const int* __restrict__ et,
                    int* __restrict__ head, int* __restrict__ srcs)
{
    int e = blockIdx.x * 256 + threadIdx.x;
    if (e < EE) {
        int pos = atomicAdd(&head[(size_t)ei[EE + e] * RR + et[e]], 1);
        srcs[pos] = ei[e];
    }
}

// ---------------------------------------------------------------------------
// lins_mfma: xl_r = x @ lins_w[r] for all 5 rels in one launch (f16 out).
// ---------------------------------------------------------------------------
__global__ __launch_bounds__(256)
void lins_mfma(const _Float16* __restrict__ xh,
               const _Float16* __restrict__ Wt0,    // wt + 384*WSTR
               _Float16* __restrict__ xl)
{
    __shared__ _Float16 Wl[DD * WSTR];
    __shared__ _Float16 Al[SLAB * WSTR];
    const int r  = blockIdx.x >> 8;
    const int s0 = blockIdx.x & 255;
    const _Float16* Wt = Wt0 + (size_t)r * DD * WSTR;
    _Float16* xlr = xl + (size_t)r * NN * DD;
    const int tid  = threadIdx.x;
    const int wv   = tid >> 6;
    const int lane = tid & 63;
    const int l15  = lane & 15;
    const int quad = lane >> 4;

    for (int u = tid; u < (DD * WSTR) / 8; u += 256)
        *(v8h*)(Wl + (size_t)u * 8) = *(const v8h*)(Wt + (size_t)u * 8);

    for (int s = s0; s < NSLAB; s += 256) {
        __syncthreads();
        #pragma unroll
        for (int j = 0; j < 2; ++j) {
            int u = tid + j * 256;
            int row = u >> 4, c8 = u & 15;
            *(v8h*)(Al + row * WSTR + c8 * 8) =
                *(const v8h*)(xh + ((size_t)s * SLAB + row) * DD + c8 * 8);
        }
        __syncthreads();

        v4f acc[2][2];
        #pragma unroll
        for (int ct = 0; ct < 2; ++ct)
            #pragma unroll
            for (int rt = 0; rt < 2; ++rt)
                acc[ct][rt] = (v4f){0.f, 0.f, 0.f, 0.f};

        #pragma unroll
        for (int ks = 0; ks < 4; ++ks) {
            v8h xf0 = *(v8h*)(Al + l15 * WSTR + ks * 32 + quad * 8);
            v8h xf1 = *(v8h*)(Al + (16 + l15) * WSTR + ks * 32 + quad * 8);
            #pragma unroll
            for (int ct = 0; ct < 2; ++ct) {
                v8h wf = *(v8h*)(Wl + (wv * 32 + ct * 16 + l15) * WSTR + ks * 32 + quad * 8);
                acc[ct][0] = __builtin_amdgcn_mfma_f32_16x16x32_f16(wf, xf0, acc[ct][0], 0, 0, 0);
                acc[ct][1] = __builtin_amdgcn_mfma_f32_16x16x32_f16(wf, xf1, acc[ct][1], 0, 0, 0);
            }
        }

        #pragma unroll
        for (int ct = 0; ct < 2; ++ct)
            #pragma unroll
            for (int rt = 0; rt < 2; ++rt) {
                const size_t row = (size_t)s * SLAB + rt * 16 + l15;
                const int c0 = wv * 32 + ct * 16 + quad * 4;
                h4 o;
                o[0] = (_Float16)acc[ct][rt][0];
                o[1] = (_Float16)acc[ct][rt][1];
                o[2] = (_Float16)acc[ct][rt][2];
                o[3] = (_Float16)acc[ct][rt][3];
                *(h4*)(xlr + row * DD + c0) = o;
            }
    }
}

// ---------------------------------------------------------------------------
// agg_skip: r1's verified agg structure + skip path fused in.
// 256 threads, chunk of 32 dsts.
//   Phase S: skip GEMM (384 cols = [x@lin | beta_s | gamma_s]) into SB
//            (stride SKSTR), barrier, per-group consume -> accT initialized
//            with relu(gamma_s*xs+beta_s)  (no oa read-back needed).
//   Phases 0..4 (exactly r1): barrier -> film GEMM rel r into SB (stride
//   BGSTR) -> barrier -> paired-window clamped gather/relu/mean -> accT.
// Final: PURE STORE of oa (skip + sum of relation means), fp32 accumulate.
// LDS: Al 8704 + SB 25088 + RP 644 ~= 34.4 KB.
// ---------------------------------------------------------------------------
__global__ __launch_bounds__(256)
void agg_skip(const int* __restrict__ rowptr,
              const int* __restrict__ srcs,
              const _Float16* __restrict__ xh,
              const _Float16* __restrict__ wt0,     // wt base (skip at 0, films at 1024)
              const float* __restrict__ fb,         // films_b
              const _Float16* __restrict__ xl,      // 5 contiguous buffers
              _Float16* __restrict__ oa)
{
    __shared__ _Float16 Al[SLAB * WSTR];            // 8704 B
    __shared__ _Float16 SB[SLAB * SKSTR];           // 25088 B (skip & film phases)
    __shared__ int RP[SLAB * RR + 1];               // 644 B

    const _Float16* wskip = wt0;                    // slots 0..383
    const _Float16* wfilm = wt0 + (size_t)1024 * WSTR;

    const int tid  = threadIdx.x;
    const int wv   = tid >> 6;
    const int lane = tid & 63;
    const int l15  = lane & 15;
    const int quad = lane >> 4;
    const int g    = tid >> 4;                      // group 0..15
    const int gl   = tid & 15;
    const int d0   = blockIdx.x * SLAB;

    // stage x rows (all 32) + rowptr slice
    #pragma unroll
    for (int j = 0; j < 2; ++j) {
        int u = tid + j * 256;
        int row = u >> 4, c8 = u & 15;
        *(v8h*)(Al + row * WSTR + c8 * 8) =
            *(const v8h*)(xh + ((size_t)(d0 + row)) * DD + c8 * 8);
    }
    if (tid <= SLAB * RR) RP[tid] = rowptr[d0 * RR + tid];
    __syncthreads();

    float accT[2][8];

    // --- Phase S: skip GEMM (6 coltiles/wave = 24 tiles = 384 cols) ---
    {
        v4f acc[6][2];
        #pragma unroll
        for (int tt = 0; tt < 6; ++tt) {
            acc[tt][0] = (v4f){0.f, 0.f, 0.f, 0.f};
            acc[tt][1] = (v4f){0.f, 0.f, 0.f, 0.f};
        }
        #pragma unroll
        for (int ks = 0; ks < 4; ++ks) {
            v8h xf0 = *(v8h*)(Al + l15 * WSTR + ks * 32 + quad * 8);
            v8h xf1 = *(v8h*)(Al + (16 + l15) * WSTR + ks * 32 + quad * 8);
            #pragma unroll
            for (int tt = 0; tt < 6; ++tt) {
                const int t = wv * 6 + tt;
                v8h wf = *(const v8h*)(wskip +
                    ((size_t)t * 16 + l15) * WSTR + ks * 32 + quad * 8);
                acc[tt][0] = __builtin_amdgcn_mfma_f32_16x16x32_f16(wf, xf0, acc[tt][0], 0, 0, 0);
                acc[tt][1] = __builtin_amdgcn_mfma_f32_16x16x32_f16(wf, xf1, acc[tt][1], 0, 0, 0);
            }
        }
        #pragma unroll
        for (int tt = 0; tt < 6; ++tt) {
            const int t  = wv * 6 + tt;
            const int f0 = t * 16 + quad * 4;
            #pragma unroll
            for (int rt = 0; rt < 2; ++rt) {
                h4 o;
                o[0] = (_Float16)acc[tt][rt][0];
                o[1] = (_Float16)acc[tt][rt][1];
                o[2] = (_Float16)acc[tt][rt][2];
                o[3] = (_Float16)acc[tt][rt][3];
                *(h4*)(SB + (size_t)(rt * 16 + l15) * SKSTR + f0) = o;
            }
        }
    }
    __syncthreads();

    // skip consume: accT = relu(gamma_s * xs + beta_s)  (pure LDS+VALU)
    #pragma unroll
    for (int sub = 0; sub < 2; ++sub) {
        const int dl = g * 2 + sub;
        const v8h xs = *(const v8h*)(SB + (size_t)dl * SKSTR + gl * 8);
        const v8h bs = *(const v8h*)(SB + (size_t)dl * SKSTR + 128 + gl * 8);
        const v8h gs = *(const v8h*)(SB + (size_t)dl * SKSTR + 256 + gl * 8);
        #pragma unroll
        for (int q = 0; q < 8; ++q)
            accT[sub][q] = fmaxf((float)gs[q] * (float)xs[q] + (float)bs[q], 0.f);
    }

    // --- film phases: exactly r1's loop (one rel per phase, SB stride BGSTR) ---
    #pragma unroll 1
    for (int r = 0; r < RR; ++r) {
        __syncthreads();    // SB free of prior readers

        v4f acc[4][2];
        #pragma unroll
        for (int tt = 0; tt < 4; ++tt) {
            acc[tt][0] = (v4f){0.f, 0.f, 0.f, 0.f};
            acc[tt][1] = (v4f){0.f, 0.f, 0.f, 0.f};
        }
        #pragma unroll
        for (int ks = 0; ks < 4; ++ks) {
            v8h xf0 = *(v8h*)(Al + l15 * WSTR + ks * 32 + quad * 8);
            v8h xf1 = *(v8h*)(Al + (16 + l15) * WSTR + ks * 32 + quad * 8);
            #pragma unroll
            for (int tt = 0; tt < 4; ++tt) {
                const int t = wv * 4 + tt;
                v8h wf = *(const v8h*)(wfilm +
                    ((size_t)r * 256 + t * 16 + l15) * WSTR + ks * 32 + quad * 8);
                acc[tt][0] = __builtin_amdgcn_mfma_f32_16x16x32_f16(wf, xf0, acc[tt][0], 0, 0, 0);
                acc[tt][1] = __builtin_amdgcn_mfma_f32_16x16x32_f16(wf, xf1, acc[tt][1], 0, 0, 0);
            }
        }
        #pragma unroll
        for (int tt = 0; tt < 4; ++tt) {
            const int t  = wv * 4 + tt;
            const int f0 = t * 16 + quad * 4;
            const float4 bia = *(const float4*)(fb + r * 2 * DD + f0);
            #pragma unroll
            for (int rt = 0; rt < 2; ++rt) {
                h4 o;
                o[0] = (_Float16)(acc[tt][rt][0] + bia.x);
                o[1] = (_Float16)(acc[tt][rt][1] + bia.y);
                o[2] = (_Float16)(acc[tt][rt][2] + bia.z);
                o[3] = (_Float16)(acc[tt][rt][3] + bia.w);
                *(h4*)(SB + (size_t)(rt * 16 + l15) * BGSTR + f0) = o;
            }
        }
        __syncthreads();

        // gather/relu/mean, paired windows for the two sub-dsts
        const _Float16* xlr = xl + (size_t)r * ((size_t)NN * DD);
        int bb2[2], kk2[2];
        int sidx[2][4];
        #pragma unroll
        for (int sub = 0; sub < 2; ++sub) {
            const int dl = g * 2 + sub;
            const int b  = RP[dl * RR + r];
            const int e  = RP[dl * RR + r + 1];
            bb2[sub] = b; kk2[sub] = e - b;
            if (kk2[sub] > 0) {
                const int kc = kk2[sub] - 1;
                #pragma unroll
                for (int j = 0; j < 4; ++j)
                    sidx[sub][j] = srcs[b + min(j, kc)];   // clamped dup
            }
        }
        v8h xv[2][4];
        #pragma unroll
        for (int sub = 0; sub < 2; ++sub) {
            if (kk2[sub] > 0) {
                #pragma unroll
                for (int j = 0; j < 4; ++j)
                    xv[sub][j] = *(const v8h*)(xlr +
                        (size_t)sidx[sub][j] * DD + gl * 8);
            }
        }
        #pragma unroll
        for (int sub = 0; sub < 2; ++sub) {
            const int k = kk2[sub];
            if (k <= 0) continue;
            const int dl = g * 2 + sub;
            const v8h bs = *(const v8h*)(SB + (size_t)dl * BGSTR + gl * 8);
            const v8h gs = *(const v8h*)(SB + (size_t)dl * BGSTR + DD + gl * 8);
            float a2[8];
            #pragma unroll
            for (int q = 0; q < 8; ++q) a2[q] = 0.f;
            #pragma unroll
            for (int j = 0; j < 4; ++j) {
                if (j < k) {
                    #pragma unroll
                    for (int q = 0; q < 8; ++q)
                        a2[q] += fmaxf((float)gs[q] * (float)xv[sub][j][q]
                                       + (float)bs[q], 0.f);
                }
            }
            // rare remainder (k > 4), batched + clamped
            int pp = bb2[sub] + 4;
            const int e = bb2[sub] + k;
            while (pp < e) {
                const int kb = min(e - pp, 4);
                int s2i[4];
                #pragma unroll
                for (int j = 0; j < 4; ++j)
                    s2i[j] = srcs[pp + min(j, kb - 1)];
                v8h x2[4];
                #pragma unroll
                for (int j = 0; j < 4; ++j)
                    x2[j] = *(const v8h*)(xlr + (size_t)s2i[j] * DD + gl * 8);
                #pragma unroll
                for (int j = 0; j < 4; ++j) {
                    if (j < kb) {
                        #pragma unroll
                        for (int q = 0; q < 8; ++q)
                            a2[q] += fmaxf((float)gs[q] * (float)x2[j][q]
                                           + (float)bs[q], 0.f);
                    }
                }
                pp += kb;
            }
            const float iv = 1.0f / (float)k;
            #pragma unroll
            for (int q = 0; q < 8; ++q) accT[sub][q] += iv * a2[q];
        }
    }

    // --- single PURE STORE of oa (skip + sum of relation means) ---
    #pragma unroll
    for (int sub = 0; sub < 2; ++sub) {
        const int d = d0 + g * 2 + sub;
        v8h nw;
        #pragma unroll
        for (int q = 0; q < 8; ++q)
            nw[q] = (_Float16)accT[sub][q];
        *(v8h*)(oa + (size_t)d * DD + gl * 8) = nw;
    }
}

// ---------------------------------------------------------------------------
// out = gelu(oa) @ linear1_w + linear1_b   (f16 in, fp32 out) (unchanged)
// ---------------------------------------------------------------------------
__global__ __launch_bounds__(256)
void final_mfma(const _Float16* __restrict__ oa,
                const _Float16* __restrict__ Wt,    // wt + 2304*WSTR
                const float* __restrict__ bias,
                float* __restrict__ out)
{
    __shared__ _Float16 Wl[DD * WSTR];
    __shared__ _Float16 Al[SLAB * WSTR];
    const int tid  = threadIdx.x;
    const int wv   = tid >> 6;
    const int lane = tid & 63;
    const int l15  = lane & 15;
    const int quad = lane >> 4;

    for (int u = tid; u < (DD * WSTR) / 8; u += 256)
        *(v8h*)(Wl + (size_t)u * 8) = *(const v8h*)(Wt + (size_t)u * 8);

    float4 bf[2];
    #pragma unroll
    for (int ct = 0; ct < 2; ++ct)
        bf[ct] = *(const float4*)(bias + wv * 32 + ct * 16 + quad * 4);

    for (int s = blockIdx.x; s < NSLAB; s += gridDim.x) {
        __syncthreads();
        #pragma unroll
        for (int j = 0; j < 2; ++j) {
            int u = tid + j * 256;
            int row = u >> 4, c8 = (u & 15) * 8;
            v8h g = *(const v8h*)(oa + ((size_t)s * SLAB + row) * DD + c8);
            v8h o;
            #pragma unroll
            for (int q = 0; q < 8; ++q)
                o[q] = (_Float16)gelu_exact((float)g[q]);
            *(v8h*)(Al + row * WSTR + c8) = o;
        }
        __syncthreads();

        v4f acc[2][2];
        #pragma unroll
        for (int ct = 0; ct < 2; ++ct)
            #pragma unroll
            for (int rt = 0; rt < 2; ++rt)
                acc[ct][rt] = (v4f){0.f, 0.f, 0.f, 0.f};

        #pragma unroll
        for (int ks = 0; ks < 4; ++ks) {
            v8h xf0 = *(v8h*)(Al + l15 * WSTR + ks * 32 + quad * 8);
            v8h xf1 = *(v8h*)(Al + (16 + l15) * WSTR + ks * 32 + quad * 8);
            v8h wf[2];
            #pragma unroll
            for (int ct = 0; ct < 2; ++ct)
                wf[ct] = *(v8h*)(Wl + (wv * 32 + ct * 16 + l15) * WSTR + ks * 32 + quad * 8);
            #pragma unroll
            for (int ct = 0; ct < 2; ++ct) {
                acc[ct][0] = __builtin_amdgcn_mfma_f32_16x16x32_f16(wf[ct], xf0, acc[ct][0], 0, 0, 0);
                acc[ct][1] = __builtin_amdgcn_mfma_f32_16x16x32_f16(wf[ct], xf1, acc[ct][1], 0, 0, 0);
            }
        }

        #pragma unroll
        for (int ct = 0; ct < 2; ++ct)
            #pragma unroll
            for (int rt = 0; rt < 2; ++rt) {
                const size_t row = (size_t)s * SLAB + rt * 16 + l15;
                const int c0 = wv * 32 + ct * 16 + quad * 4;
                float4 o;
                o.x = acc[ct][rt][0] + bf[ct].x;
                o.y = acc[ct][rt][1] + bf[ct].y;
                o.z = acc[ct][rt][2] + bf[ct].z;
                o.w = acc[ct][rt][3] + bf[ct].w;
                *(float4*)(out + row * DD + c0) = o;
            }
    }
}

extern "C" void kernel_launch(void* const* d_in, const int* in_sizes, int n_in,
                              void* d_out, int out_size, void* d_ws, size_t ws_size,
                              hipStream_t stream)
{
    const float* x           = (const float*)d_in[0];
    const int*   ei          = (const int*)d_in[1];
    const int*   et          = (const int*)d_in[2];
    const float* lin_skip_w  = (const float*)d_in[3];
    const float* film_skip_w = (const float*)d_in[4];
    const float* lins_w      = (const float*)d_in[5];
    const float* films_w     = (const float*)d_in[6];
    const float* films_b     = (const float*)d_in[7];
    const float* linear1_w   = (const float*)d_in[8];
    const float* linear1_b   = (const float*)d_in[9];
    float* out = (float*)d_out;
    char*  ws  = (char*)d_ws;

    // workspace layout (bytes, f16 regions 256-aligned) — ~190.3 MB total
    _Float16* xh      = (_Float16*)(ws);                   // 25,600,000
    _Float16* wt      = (_Float16*)(ws + 25600000);        //    661,504
    _Float16* xl      = (_Float16*)(ws + 26261504);        // 5 x 25,600,000
    _Float16* oa      = (_Float16*)(ws + 154261504);       // 25,600,000
    int*      cnt     = (int*)     (ws + 179861504);       //  2,000,000
    int*      partial = (int*)     (ws + 181861504);       //  2,000,000
    int*      rowptr  = (int*)     (ws + 183861504);       //  2,000,128
    int*      head    = (int*)     (ws + 185861632);       //  2,000,000
    int*      srcs    = (int*)     (ws + 187861632);       //  2,400,256 (+pad)
    int*      bsum    = (int*)     (ws + 190261888);       //      4,096
    int*      bsum2   = (int*)     (ws + 190265984);       //      4,096

    prep<<<CONV_BLKS + ZERO_BLKS + TW_BLKS, 256, 0, stream>>>(
        x, xh, cnt, lin_skip_w, film_skip_w, lins_w, films_w, linear1_w, wt);

    // counting sort of edges by (dst, rel) — separate launches (grid.sync
    // on MI355X costs ~65 us each; kernel boundaries are far cheaper)
    count_kernel<<<(EE + 255) / 256, 256, 0, stream>>>(ei, et, cnt);
    scan1<<<NB1, 256, 0, stream>>>(cnt, partial, bsum);
    scan2<<<1, 512, 0, stream>>>(bsum, bsum2);
    scan3<<<NB1, 256, 0, stream>>>(partial, bsum2, rowptr, head, srcs);
    scatter_kernel<<<(EE + 255) / 256, 256, 0, stream>>>(ei, et, head, srcs);

    // xl_r for all 5 relations (one launch)
    lins_mfma<<<1280, 256, 0, stream>>>(xh, wt + (size_t)384 * WSTR, xl);

    // fused: skip path + per-rel FiLM GEMM + paired-window gather/mean
    agg_skip<<<NSLAB, 256, 0, stream>>>(rowptr, srcs, xh, wt,
                                        films_b, xl, oa);

    final_mfma<<<512, 256, 0, stream>>>(oa, wt + (size_t)2304 * WSTR,
                                        linear1_b, out);
}